// Round 6
// baseline (212.025 us; speedup 1.0000x reference)
//
#include <hip/hip_runtime.h>

#define S_LEN 2048
#define DMODEL 1024
#define NHEAD 16
#define DHEAD 64
#define BATCH 2
#define BH_TOT (BATCH * NHEAD)   // 32
#define TOK (BATCH * S_LEN)      // 4096
#define NQKV (3 * DMODEL)        // 3072

// softmax scale 1/sqrt(64) = 0.125, fused with log2(e) so scores are in log2 domain
#define QSCALE 0.18033688011112042f

typedef float  f32x4  __attribute__((ext_vector_type(4)));
typedef float  f32x16 __attribute__((ext_vector_type(16)));
typedef int    i32x4  __attribute__((ext_vector_type(4)));
typedef unsigned u32x2 __attribute__((ext_vector_type(2)));
typedef __bf16 bf16x8 __attribute__((ext_vector_type(8)));
typedef __bf16 bf16x4 __attribute__((ext_vector_type(4)));
typedef __bf16 bf16x2 __attribute__((ext_vector_type(2)));

typedef __attribute__((address_space(1))) void* as1_ptr;
typedef __attribute__((address_space(3))) void* as3_ptr;

__device__ __forceinline__ void gl2lds16(const void* g, void* l) {
  __builtin_amdgcn_global_load_lds((as1_ptr)(void*)g, (as3_ptr)l, 16, 0, 0);
}

__device__ __forceinline__ f32x4 mfma32(bf16x8 a, bf16x8 b, f32x4 c) {
  return __builtin_amdgcn_mfma_f32_16x16x32_bf16(a, b, c, 0, 0, 0);
}

// 32x32x16 bf16: A[m=lane&31][k=(lane>>5)*8+j], B[k=(lane>>5)*8+j][n=lane&31]
// C/D: col=lane&31, row=(reg&3)+8*(reg>>2)+4*(lane>>5)
__device__ __forceinline__ f32x16 mfma3216(bf16x8 a, bf16x8 b, f32x16 c) {
  return __builtin_amdgcn_mfma_f32_32x32x16_bf16(a, b, c, 0, 0, 0);
}

// pack 2 f32 -> 1 word of 2 bf16 via scalar casts (compiler emits the pack)
__device__ __forceinline__ unsigned pack2(float a, float b) {
  bf16x2 t;
  t[0] = (__bf16)a;
  t[1] = (__bf16)b;
  return __builtin_bit_cast(unsigned, t);
}

// P B-fragment in the PERMUTED k-slot order (zero cross-lane ops).
// Slot (hi,j) <-> key 4*hi + (j<4 ? j : 4+j). P's natural post-QK^T register order
// p[r]=P[key=(r&3)+8*(r>>2)+4*hi] for r=0..7 is exactly this order packed pairwise.
__device__ __forceinline__ bf16x8 pfragn(float a0, float a1, float a2, float a3,
                                         float a4, float a5, float a6, float a7) {
  const i32x4 w = {(int)pack2(a0, a1), (int)pack2(a2, a3),
                   (int)pack2(a4, a5), (int)pack2(a6, a7)};
  return __builtin_bit_cast(bf16x8, w);
}

// ---------------------------------------------------------------- convert f32 -> bf16
__global__ __launch_bounds__(256) void cvt_kernel(const float* __restrict__ src,
                                                  __bf16* __restrict__ dst, int n) {
  const int i = (blockIdx.x * 256 + threadIdx.x) * 4;
  if (i >= n) return;
  const f32x4 v = *(const f32x4*)(src + i);
  bf16x4 o;
  o[0] = (__bf16)v[0]; o[1] = (__bf16)v[1]; o[2] = (__bf16)v[2]; o[3] = (__bf16)v[3];
  *(bf16x4*)(dst + i) = o;
}

// ---------------------------------------------------------------- 128x128 bf16 GEMM mainloop
__device__ __forceinline__ void gemm_tile_128(const __bf16* __restrict__ A,
                                              const __bf16* __restrict__ Bw,
                                              const int Kd, const int tileM, const int tileN,
                                              __bf16* As, __bf16* Bs, f32x4 acc[4][4]) {
  const int t    = threadIdx.x;
  const int lane = t & 63;
  const int wave = t >> 6;
  const int quad = lane >> 4;
  const int c    = lane & 15;
  const int wm   = (wave >> 1) << 6;
  const int wn   = (wave & 1) << 6;

  const int u0 = t, u1 = t + 256;
  const __bf16* gA0 = A  + (size_t)(tileM + (u0 >> 2)) * Kd + (u0 & 3) * 8;
  const __bf16* gA1 = A  + (size_t)(tileM + (u1 >> 2)) * Kd + (u1 & 3) * 8;
  const __bf16* gB0 = Bw + (size_t)(tileN + (u0 >> 2)) * Kd + (u0 & 3) * 8;
  const __bf16* gB1 = Bw + (size_t)(tileN + (u1 >> 2)) * Kd + (u1 & 3) * 8;
  __bf16* lA0 = As + u0 * 8; __bf16* lA1 = As + u1 * 8;
  __bf16* lB0 = Bs + u0 * 8; __bf16* lB1 = Bs + u1 * 8;

  for (int k0 = 0; k0 < Kd; k0 += 32) {
    gl2lds16(gA0 + k0, lA0);
    gl2lds16(gA1 + k0, lA1);
    gl2lds16(gB0 + k0, lB0);
    gl2lds16(gB1 + k0, lB1);
    __syncthreads();
    bf16x8 af[4], bfr[4];
#pragma unroll
    for (int mt = 0; mt < 4; ++mt)
      af[mt] = *(const bf16x8*)(As + (wm + mt * 16 + c) * 32 + quad * 8);
#pragma unroll
    for (int nt = 0; nt < 4; ++nt)
      bfr[nt] = *(const bf16x8*)(Bs + (wn + nt * 16 + c) * 32 + quad * 8);
#pragma unroll
    for (int mt = 0; mt < 4; ++mt)
#pragma unroll
      for (int nt = 0; nt < 4; ++nt)
        acc[mt][nt] = mfma32(af[mt], bfr[nt], acc[mt][nt]);
    __syncthreads();
  }
}

// ---------------------------------------------------------------- QKV projection (+V transpose fused, +Q log2-scale)
__global__ __launch_bounds__(256) void gemm_qkv_kernel(const __bf16* __restrict__ xb,
                                                       const __bf16* __restrict__ Wb,
                                                       const float* __restrict__ bias,
                                                       __bf16* __restrict__ Qb,
                                                       __bf16* __restrict__ Kb,
                                                       __bf16* __restrict__ Vtb) {
  __shared__ __align__(16) __bf16 As[128 * 32];
  __shared__ __align__(16) __bf16 Bs[128 * 32];
  f32x4 acc[4][4];
#pragma unroll
  for (int i = 0; i < 4; ++i)
#pragma unroll
    for (int j = 0; j < 4; ++j) acc[i][j] = (f32x4){0.f, 0.f, 0.f, 0.f};

  const int tileM = blockIdx.y * 128;
  const int tileN = blockIdx.x * 128;
  gemm_tile_128(xb, Wb, DMODEL, tileM, tileN, As, Bs, acc);

  const int t = threadIdx.x;
  const int lane = t & 63, wave = t >> 6;
  const int quad = lane >> 4, c = lane & 15;
  const int wm = (wave >> 1) << 6, wn = (wave & 1) << 6;

#pragma unroll
  for (int nt = 0; nt < 4; ++nt) {
    const int col = tileN + wn + nt * 16 + c;
    const float bv = bias[col];
    const int which = col >> 10;         // 0=q,1=k,2=v  (uniform within 16-col group)
    const int h  = (col >> 6) & 15;
    const int dh = col & 63;
    if (which == 2) {
#pragma unroll
      for (int mt = 0; mt < 4; ++mt) {
        const int row0 = tileM + wm + mt * 16 + quad * 4;
        const int bb = row0 >> 11;
        const int ss = row0 & (S_LEN - 1);
        bf16x4 o;
#pragma unroll
        for (int r = 0; r < 4; ++r) o[r] = (__bf16)(acc[mt][nt][r] + bv);
        *(bf16x4*)(Vtb + (((size_t)(bb * NHEAD + h)) * DHEAD + dh) * S_LEN + ss) = o;
      }
    } else {
      __bf16* dst = (which == 0) ? Qb : Kb;
      const float scl = (which == 0) ? QSCALE : 1.0f;
#pragma unroll
      for (int mt = 0; mt < 4; ++mt) {
#pragma unroll
        for (int r = 0; r < 4; ++r) {
          const int row = tileM + wm + mt * 16 + quad * 4 + r;
          const int bb = row >> 11;
          const int ss = row & (S_LEN - 1);
          dst[(((size_t)(bb * NHEAD + h)) * S_LEN + ss) * DHEAD + dh] =
              (__bf16)((acc[mt][nt][r] + bv) * scl);
        }
      }
    }
  }
}

// ---------------------------------------------------------------- output projection
__global__ __launch_bounds__(256) void gemm_out_kernel(const __bf16* __restrict__ AOb,
                                                       const __bf16* __restrict__ Wb,
                                                       const float* __restrict__ bout,
                                                       float* __restrict__ out) {
  __shared__ __align__(16) __bf16 As[128 * 32];
  __shared__ __align__(16) __bf16 Bs[128 * 32];
  f32x4 acc[4][4];
#pragma unroll
  for (int i = 0; i < 4; ++i)
#pragma unroll
    for (int j = 0; j < 4; ++j) acc[i][j] = (f32x4){0.f, 0.f, 0.f, 0.f};

  const int tileM = blockIdx.y * 128;
  const int tileN = blockIdx.x * 128;
  gemm_tile_128(AOb, Wb, DMODEL, tileM, tileN, As, Bs, acc);

  const int t = threadIdx.x;
  const int lane = t & 63, wave = t >> 6;
  const int quad = lane >> 4, c = lane & 15;
  const int wm = (wave >> 1) << 6, wn = (wave & 1) << 6;

#pragma unroll
  for (int nt = 0; nt < 4; ++nt) {
    const int col = tileN + wn + nt * 16 + c;
    const float bv = bout[col];
#pragma unroll
    for (int mt = 0; mt < 4; ++mt) {
#pragma unroll
      for (int r = 0; r < 4; ++r) {
        const int row = tileM + wm + mt * 16 + quad * 4 + r;
        out[(size_t)row * DMODEL + col] = acc[mt][nt][r] + bv;
      }
    }
  }
}

// ---------------------------------------------------------------- partial interleaved RoPE
__global__ __launch_bounds__(256) void rope_kernel(__bf16* __restrict__ Qb, __bf16* __restrict__ Kb) {
  const int idx = blockIdx.x * 256 + threadIdx.x;
  const int j  = idx & 15;
  const int s  = (idx >> 4) & (S_LEN - 1);
  const int bh = (idx >> 15) & (BH_TOT - 1);
  __bf16* base = (idx >> 20) ? Kb : Qb;
  bf16x2* p = (bf16x2*)(base + ((size_t)bh * S_LEN + s) * DHEAD) + j;
  bf16x2 v = *p;
  const float x1 = (float)v[0];
  const float x2 = (float)v[1];
  const float LOG2_10000 = 13.287712379549449f;
  const float inv = exp2f(-(float)j * (LOG2_10000 / 16.0f));
  const float ang = (float)s * inv;
  float sn, cs;
  sincosf(ang, &sn, &cs);
  bf16x2 o;
  o[0] = (__bf16)(x1 * cs - x2 * sn);
  o[1] = (__bf16)(x2 * cs + x1 * sn);
  *p = o;
}

// ---------------------------------------------------------------- flash attention R7b
// 1 wave per block, 32 q per wave; grid (64, 32) = 2048 independent blocks (8/CU).
// KVBLK=32; K/V^T double-buffered in LDS (16 KB/block) via global_load_lds.
// STATIC buffer indices (kb-loop unrolled x2) so Ks[0]/Ks[1] are compile-time
// distinct -> the waitcnt pass cannot conservatively drain the prefetch.
// Single-wave block => no barrier needed at all: explicit s_waitcnt vmcnt(0)
// drains this wave's DMA (robust against s_barrier elision for 1-wave groups).
// Body order: vmcnt(0) -> ds_read cur (K b128 x4 + V b64 x8) -> sched_barrier ->
// stage next (8x gl2lds) -> QK MFMA x4 -> exp x16 -> zero-shuffle P-frags ->
// PV MFMA x4.
// K swizzle: 16B chunk ^= row&7 (8-chunk rows). V^T swizzle: chunk ^= (row>>1)&3
// (4-chunk rows; spreads banks to the b64 floor).
__global__ __launch_bounds__(64, 2) void attn_kernel(const __bf16* __restrict__ Qb,
                                                     const __bf16* __restrict__ Kb,
                                                     const __bf16* __restrict__ Vtb,
                                                     __bf16* __restrict__ AOb) {
  __shared__ __align__(16) __bf16 Ks[2][32 * 64];   // [key][d], swizzled, 4 KB each
  __shared__ __align__(16) __bf16 Vts[2][64 * 32];  // [d][key], swizzled, 4 KB each

  const int qt = blockIdx.x;           // 0..63
  const int bh = blockIdx.y;
  const int b = bh >> 4, h = bh & 15;
  const int lane = threadIdx.x & 63;
  const int c31 = lane & 31, hi = lane >> 5;
  const int cx7 = c31 & 7;             // K-row swizzle key (row = c31)
  const int cxv = (c31 >> 1) & 3;      // V-row swizzle key (row = db*32+c31; db*32 = 0 mod 4*2)
  const size_t head = (size_t)bh * S_LEN * DHEAD;
  const int q0w = qt * 32;             // this wave's first q

  // Q B-frags (resident): qf[s] = Q^T[k=d=s*16+hi*8+j][n=q=q0w+c31]
  bf16x8 qf[4];
#pragma unroll
  for (int s = 0; s < 4; ++s)
    qf[s] = *(const bf16x8*)(Qb + head + (size_t)(q0w + c31) * DHEAD + s * 16 + hi * 8);

  f32x16 zzero;
#pragma unroll
  for (int i = 0; i < 16; ++i) zzero[i] = 0.f;

  // O^T accumulators: lane holds d = db*32+(r&3)+8*(r>>2)+4*hi, q = c31.
  // ota <- 16-key chunk kc=0 of each tile, otb <- kc=1; summed in the epilogue.
  f32x16 ota[2], otb[2];
  ota[0] = zzero; ota[1] = zzero; otb[0] = zzero; otb[1] = zzero;
  float lp = 0.f;

  // staging: K tile = 256 16B units (row=u>>3 of 32, chunk=(u&7)^(row&7));
  //          V tile = 256 16B units (row=u>>2 of 64, chunk=(u&3)^((row>>1)&3));
  // 64 lanes x 4 units each; LDS dst linear (u*16B), source pre-swizzled.
  const __bf16* kg[4];
  const __bf16* vg[4];
  int lofK[4], lofV[4];
#pragma unroll
  for (int i = 0; i < 4; ++i) {
    const int u = lane + 64 * i;
    const int rk = u >> 3, ck = (u & 7) ^ (rk & 7);
    kg[i] = Kb + head + (size_t)rk * DHEAD + ck * 8;
    lofK[i] = u * 8;
    const int rv = u >> 2, cv = (u & 3) ^ ((rv >> 1) & 3);
    vg[i] = Vtb + ((size_t)bh * DHEAD + rv) * S_LEN + cv * 8;
    lofV[i] = u * 8;
  }

  // prologue: stage tile 0 into buffer 0
#pragma unroll
  for (int i = 0; i < 4; ++i) {
    gl2lds16(kg[i], &Ks[0][lofK[i]]);
    gl2lds16(vg[i], &Vts[0][lofV[i]]);
  }

// V^T A-frag (permuted k-slot order): element (hi,j) = V^T[d=db*32+c31][key=kc*16+4hi+(j<4?j:4+j)]
// = two b64 reads at 16B chunks kc*2, kc*2+1 (XOR-swizzled), byte offset hi*8.
#define VFRAG(CUR, db, kc)                                                                 \
  __builtin_bit_cast(bf16x8, (i32x4){                                                      \
      (int)__builtin_bit_cast(u32x2, *(const bf16x4*)(&Vts[CUR][((db) * 32 + c31) * 32 +   \
                                     ((((kc) * 2) ^ cxv) * 8) + hi * 4]))[0],              \
      (int)__builtin_bit_cast(u32x2, *(const bf16x4*)(&Vts[CUR][((db) * 32 + c31) * 32 +   \
                                     ((((kc) * 2) ^ cxv) * 8) + hi * 4]))[1],              \
      (int)__builtin_bit_cast(u32x2, *(const bf16x4*)(&Vts[CUR][((db) * 32 + c31) * 32 +   \
                                     ((((kc) * 2 + 1) ^ cxv) * 8) + hi * 4]))[0],          \
      (int)__builtin_bit_cast(u32x2, *(const bf16x4*)(&Vts[CUR][((db) * 32 + c31) * 32 +   \
                                     ((((kc) * 2 + 1) ^ cxv) * 8) + hi * 4]))[1]})

#define ATTN_TILE(KB, CUR)                                                                 \
  {                                                                                        \
    asm volatile("s_waitcnt vmcnt(0)" ::: "memory");                                       \
    __builtin_amdgcn_sched_barrier(0);                                                     \
    bf16x8 kA[4];                                                                          \
    _Pragma("unroll")                                                                      \
    for (int s = 0; s < 4; ++s)                                                            \
      kA[s] = *(const bf16x8*)(&Ks[CUR][c31 * 64 + (((s * 2 + hi) ^ cx7) * 8)]);           \
    const bf16x8 vA00 = VFRAG(CUR, 0, 0);                                                  \
    const bf16x8 vA10 = VFRAG(CUR, 1, 0);                                                  \
    const bf16x8 vA01 = VFRAG(CUR, 0, 1);                                                  \
    const bf16x8 vA11 = VFRAG(CUR, 1, 1);                                                  \
    __builtin_amdgcn_sched_barrier(0);                                                     \
    if ((KB) + 1 < S_LEN / 32) {                                                           \
      const int ka = ((KB) + 1) * (32 * DHEAD);                                            \
      const int va = ((KB) + 1) * 32;                                                      \
      _Pragma("unroll")                                                                    \
      for (int i = 0; i < 4; ++i) {                                                        \
        gl2lds16(kg[i] + ka, &Ks[(CUR) ^ 1][lofK[i]]);                                     \
        gl2lds16(vg[i] + va, &Vts[(CUR) ^ 1][lofV[i]]);                                    \
      }                                                                                    \
    }                                                                                      \
    __builtin_amdgcn_sched_barrier(0);                                                     \
    f32x16 z = zzero;                                                                      \
    __builtin_amdgcn_s_setprio(1);                                                         \
    _Pragma("unroll")                                                                      \
    for (int s = 0; s < 4; ++s) z = mfma3216(kA[s], qf[s], z);                             \
    __builtin_amdgcn_s_setprio(0);                                                         \
    float p[16];                                                                           \
    _Pragma("unroll")                                                                      \
    for (int r = 0; r < 16; ++r) p[r] = __builtin_amdgcn_exp2f(z[r]);                      \
    lp += (((p[0] + p[1]) + (p[2] + p[3])) + ((p[4] + p[5]) + (p[6] + p[7])))              \
        + (((p[8] + p[9]) + (p[10] + p[11])) + ((p[12] + p[13]) + (p[14] + p[15])));       \
    const bf16x8 f0 = pfragn(p[0], p[1], p[2], p[3], p[4], p[5], p[6], p[7]);              \
    const bf16x8 f1 = pfragn(p[8], p[9], p[10], p[11], p[12], p[13], p[14], p[15]);        \
    __builtin_amdgcn_s_setprio(1);                                                         \
    ota[0] = mfma3216(vA00, f0, ota[0]);                                                   \
    ota[1] = mfma3216(vA10, f0, ota[1]);                                                   \
    otb[0] = mfma3216(vA01, f1, otb[0]);                                                   \
    otb[1] = mfma3216(vA11, f1, otb[1]);                                                   \
    __builtin_amdgcn_s_setprio(0);                                                         \
  }

  for (int kbb = 0; kbb < S_LEN / 64; ++kbb) {
    ATTN_TILE(2 * kbb, 0)
    ATTN_TILE(2 * kbb + 1, 1)
  }
#undef ATTN_TILE
#undef VFRAG

  // epilogue: merge split accumulators; l over full key range = lp + partner-half lp
#pragma unroll
  for (int i = 0; i < 16; ++i) { ota[0][i] += otb[0][i]; ota[1][i] += otb[1][i]; }
  const float l = lp + __shfl_xor(lp, 32);
  const float inv = 1.0f / l;
  const int q = q0w + c31;
#pragma unroll
  for (int db = 0; db < 2; ++db) {
#pragma unroll
    for (int rg = 0; rg < 4; ++rg) {
      bf16x4 o;
#pragma unroll
      for (int i = 0; i < 4; ++i) o[i] = (__bf16)(ota[db][rg * 4 + i] * inv);
      const int d0 = db * 32 + rg * 8 + hi * 4;
      *(bf16x4*)(AOb + ((size_t)(b * S_LEN + q)) * DMODEL + h * DHEAD + d0) = o;
    }
  }
}

// ---------------------------------------------------------------- launch
extern "C" void kernel_launch(void* const* d_in, const int* in_sizes, int n_in,
                              void* d_out, int out_size, void* d_ws, size_t ws_size,
                              hipStream_t stream) {
  const float* x    = (const float*)d_in[0];
  const float* Wqkv = (const float*)d_in[1];
  const float* bqkv = (const float*)d_in[2];
  const float* Wout = (const float*)d_in[3];
  const float* bout = (const float*)d_in[4];
  float* out = (float*)d_out;

  char* ws = (char*)d_ws;
  __bf16* xb    = (__bf16*)(ws + 0);                          //  8 MB (4096x1024)
  __bf16* Wqkvb = (__bf16*)(ws + (size_t)8  * 1024 * 1024);   //  6 MB (3072x1024)
  __bf16* Woutb = (__bf16*)(ws + (size_t)14 * 1024 * 1024);   //  2 MB (1024x1024)
  __bf16* Qb    = (__bf16*)(ws + (size_t)16 * 1024 * 1024);   //  8 MB [bh][s][d] (pre-scaled)
  __bf16* Kb    = (__bf16*)(ws + (size_t)24 * 1024 * 1024);   //  8 MB [bh][s][d]
  __bf16* Vtb   = (__bf16*)(ws + (size_t)32 * 1024 * 1024);   //  8 MB [bh][d][s]
  __bf16* AOb   = (__bf16*)(ws + (size_t)40 * 1024 * 1024);   //  8 MB [b][s][dm]

  cvt_kernel<<<(TOK * DMODEL) / 1024, 256, 0, stream>>>(x, xb, TOK * DMODEL);
  cvt_kernel<<<(NQKV * DMODEL) / 1024, 256, 0, stream>>>(Wqkv, Wqkvb, NQKV * DMODEL);
  cvt_kernel<<<(DMODEL * DMODEL) / 1024, 256, 0, stream>>>(Wout, Woutb, DMODEL * DMODEL);

  gemm_qkv_kernel<<<dim3(NQKV / 128, TOK / 128), 256, 0, stream>>>(xb, Wqkvb, bqkv, Qb, Kb, Vtb);

  rope_kernel<<<(2 * BH_TOT * S_LEN * 16) / 256, 256, 0, stream>>>(Qb, Kb);

  attn_kernel<<<dim3(S_LEN / 32, BH_TOT), 64, 0, stream>>>(Qb, Kb, Vtb, AOb);

  gemm_out_kernel<<<dim3(DMODEL / 128, TOK / 128), 256, 0, stream>>>(AOb, Woutb, bout, out);
}

// Round 7
// 211.605 us; speedup vs baseline: 1.0020x; 1.0020x over previous
//
#include <hip/hip_runtime.h>

#define S_LEN 2048
#define DMODEL 1024
#define NHEAD 16
#define DHEAD 64
#define BATCH 2
#define BH_TOT (BATCH * NHEAD)   // 32
#define TOK (BATCH * S_LEN)      // 4096
#define NQKV (3 * DMODEL)        // 3072

// softmax scale 1/sqrt(64) = 0.125, fused with log2(e) so scores are in log2 domain
#define QSCALE 0.18033688011112042f

typedef float  f32x4  __attribute__((ext_vector_type(4)));
typedef float  f32x16 __attribute__((ext_vector_type(16)));
typedef int    i32x4  __attribute__((ext_vector_type(4)));
typedef unsigned u32x2 __attribute__((ext_vector_type(2)));
typedef __bf16 bf16x8 __attribute__((ext_vector_type(8)));
typedef __bf16 bf16x4 __attribute__((ext_vector_type(4)));
typedef __bf16 bf16x2 __attribute__((ext_vector_type(2)));

typedef __attribute__((address_space(1))) void* as1_ptr;
typedef __attribute__((address_space(3))) void* as3_ptr;

__device__ __forceinline__ void gl2lds16(const void* g, void* l) {
  __builtin_amdgcn_global_load_lds((as1_ptr)(void*)g, (as3_ptr)l, 16, 0, 0);
}

__device__ __forceinline__ f32x4 mfma32(bf16x8 a, bf16x8 b, f32x4 c) {
  return __builtin_amdgcn_mfma_f32_16x16x32_bf16(a, b, c, 0, 0, 0);
}

// 32x32x16 bf16: A[m=lane&31][k=(lane>>5)*8+j], B[k=(lane>>5)*8+j][n=lane&31]
// C/D: col=lane&31, row=(reg&3)+8*(reg>>2)+4*(lane>>5)
__device__ __forceinline__ f32x16 mfma3216(bf16x8 a, bf16x8 b, f32x16 c) {
  return __builtin_amdgcn_mfma_f32_32x32x16_bf16(a, b, c, 0, 0, 0);
}

// pack 2 f32 -> 1 word of 2 bf16 via scalar casts (compiler emits the pack)
__device__ __forceinline__ unsigned pack2(float a, float b) {
  bf16x2 t;
  t[0] = (__bf16)a;
  t[1] = (__bf16)b;
  return __builtin_bit_cast(unsigned, t);
}

// P B-fragment in the PERMUTED k-slot order (zero cross-lane ops).
// Slot (hi,j) <-> key 4*hi + (j<4 ? j : 4+j). P's natural post-QK^T register order
// p[r]=P[key=(r&3)+8*(r>>2)+4*hi] for r=0..7 is exactly this order packed pairwise.
__device__ __forceinline__ bf16x8 pfragn(float a0, float a1, float a2, float a3,
                                         float a4, float a5, float a6, float a7) {
  const i32x4 w = {(int)pack2(a0, a1), (int)pack2(a2, a3),
                   (int)pack2(a4, a5), (int)pack2(a6, a7)};
  return __builtin_bit_cast(bf16x8, w);
}

// ---------------------------------------------------------------- convert f32 -> bf16
__global__ __launch_bounds__(256) void cvt_kernel(const float* __restrict__ src,
                                                  __bf16* __restrict__ dst, int n) {
  const int i = (blockIdx.x * 256 + threadIdx.x) * 4;
  if (i >= n) return;
  const f32x4 v = *(const f32x4*)(src + i);
  bf16x4 o;
  o[0] = (__bf16)v[0]; o[1] = (__bf16)v[1]; o[2] = (__bf16)v[2]; o[3] = (__bf16)v[3];
  *(bf16x4*)(dst + i) = o;
}

// ---------------------------------------------------------------- 128x128 bf16 GEMM mainloop
__device__ __forceinline__ void gemm_tile_128(const __bf16* __restrict__ A,
                                              const __bf16* __restrict__ Bw,
                                              const int Kd, const int tileM, const int tileN,
                                              __bf16* As, __bf16* Bs, f32x4 acc[4][4]) {
  const int t    = threadIdx.x;
  const int lane = t & 63;
  const int wave = t >> 6;
  const int quad = lane >> 4;
  const int c    = lane & 15;
  const int wm   = (wave >> 1) << 6;
  const int wn   = (wave & 1) << 6;

  const int u0 = t, u1 = t + 256;
  const __bf16* gA0 = A  + (size_t)(tileM + (u0 >> 2)) * Kd + (u0 & 3) * 8;
  const __bf16* gA1 = A  + (size_t)(tileM + (u1 >> 2)) * Kd + (u1 & 3) * 8;
  const __bf16* gB0 = Bw + (size_t)(tileN + (u0 >> 2)) * Kd + (u0 & 3) * 8;
  const __bf16* gB1 = Bw + (size_t)(tileN + (u1 >> 2)) * Kd + (u1 & 3) * 8;
  __bf16* lA0 = As + u0 * 8; __bf16* lA1 = As + u1 * 8;
  __bf16* lB0 = Bs + u0 * 8; __bf16* lB1 = Bs + u1 * 8;

  for (int k0 = 0; k0 < Kd; k0 += 32) {
    gl2lds16(gA0 + k0, lA0);
    gl2lds16(gA1 + k0, lA1);
    gl2lds16(gB0 + k0, lB0);
    gl2lds16(gB1 + k0, lB1);
    __syncthreads();
    bf16x8 af[4], bfr[4];
#pragma unroll
    for (int mt = 0; mt < 4; ++mt)
      af[mt] = *(const bf16x8*)(As + (wm + mt * 16 + c) * 32 + quad * 8);
#pragma unroll
    for (int nt = 0; nt < 4; ++nt)
      bfr[nt] = *(const bf16x8*)(Bs + (wn + nt * 16 + c) * 32 + quad * 8);
#pragma unroll
    for (int mt = 0; mt < 4; ++mt)
#pragma unroll
      for (int nt = 0; nt < 4; ++nt)
        acc[mt][nt] = mfma32(af[mt], bfr[nt], acc[mt][nt]);
    __syncthreads();
  }
}

// ---------------------------------------------------------------- QKV projection (+V transpose fused, +Q log2-scale)
__global__ __launch_bounds__(256) void gemm_qkv_kernel(const __bf16* __restrict__ xb,
                                                       const __bf16* __restrict__ Wb,
                                                       const float* __restrict__ bias,
                                                       __bf16* __restrict__ Qb,
                                                       __bf16* __restrict__ Kb,
                                                       __bf16* __restrict__ Vtb) {
  __shared__ __align__(16) __bf16 As[128 * 32];
  __shared__ __align__(16) __bf16 Bs[128 * 32];
  f32x4 acc[4][4];
#pragma unroll
  for (int i = 0; i < 4; ++i)
#pragma unroll
    for (int j = 0; j < 4; ++j) acc[i][j] = (f32x4){0.f, 0.f, 0.f, 0.f};

  const int tileM = blockIdx.y * 128;
  const int tileN = blockIdx.x * 128;
  gemm_tile_128(xb, Wb, DMODEL, tileM, tileN, As, Bs, acc);

  const int t = threadIdx.x;
  const int lane = t & 63, wave = t >> 6;
  const int quad = lane >> 4, c = lane & 15;
  const int wm = (wave >> 1) << 6, wn = (wave & 1) << 6;

#pragma unroll
  for (int nt = 0; nt < 4; ++nt) {
    const int col = tileN + wn + nt * 16 + c;
    const float bv = bias[col];
    const int which = col >> 10;         // 0=q,1=k,2=v  (uniform within 16-col group)
    const int h  = (col >> 6) & 15;
    const int dh = col & 63;
    if (which == 2) {
#pragma unroll
      for (int mt = 0; mt < 4; ++mt) {
        const int row0 = tileM + wm + mt * 16 + quad * 4;
        const int bb = row0 >> 11;
        const int ss = row0 & (S_LEN - 1);
        bf16x4 o;
#pragma unroll
        for (int r = 0; r < 4; ++r) o[r] = (__bf16)(acc[mt][nt][r] + bv);
        *(bf16x4*)(Vtb + (((size_t)(bb * NHEAD + h)) * DHEAD + dh) * S_LEN + ss) = o;
      }
    } else {
      __bf16* dst = (which == 0) ? Qb : Kb;
      const float scl = (which == 0) ? QSCALE : 1.0f;
#pragma unroll
      for (int mt = 0; mt < 4; ++mt) {
#pragma unroll
        for (int r = 0; r < 4; ++r) {
          const int row = tileM + wm + mt * 16 + quad * 4 + r;
          const int bb = row >> 11;
          const int ss = row & (S_LEN - 1);
          dst[(((size_t)(bb * NHEAD + h)) * S_LEN + ss) * DHEAD + dh] =
              (__bf16)((acc[mt][nt][r] + bv) * scl);
        }
      }
    }
  }
}

// ---------------------------------------------------------------- output projection
__global__ __launch_bounds__(256) void gemm_out_kernel(const __bf16* __restrict__ AOb,
                                                       const __bf16* __restrict__ Wb,
                                                       const float* __restrict__ bout,
                                                       float* __restrict__ out) {
  __shared__ __align__(16) __bf16 As[128 * 32];
  __shared__ __align__(16) __bf16 Bs[128 * 32];
  f32x4 acc[4][4];
#pragma unroll
  for (int i = 0; i < 4; ++i)
#pragma unroll
    for (int j = 0; j < 4; ++j) acc[i][j] = (f32x4){0.f, 0.f, 0.f, 0.f};

  const int tileM = blockIdx.y * 128;
  const int tileN = blockIdx.x * 128;
  gemm_tile_128(AOb, Wb, DMODEL, tileM, tileN, As, Bs, acc);

  const int t = threadIdx.x;
  const int lane = t & 63, wave = t >> 6;
  const int quad = lane >> 4, c = lane & 15;
  const int wm = (wave >> 1) << 6, wn = (wave & 1) << 6;

#pragma unroll
  for (int nt = 0; nt < 4; ++nt) {
    const int col = tileN + wn + nt * 16 + c;
    const float bv = bout[col];
#pragma unroll
    for (int mt = 0; mt < 4; ++mt) {
#pragma unroll
      for (int r = 0; r < 4; ++r) {
        const int row = tileM + wm + mt * 16 + quad * 4 + r;
        out[(size_t)row * DMODEL + col] = acc[mt][nt][r] + bv;
      }
    }
  }
}

// ---------------------------------------------------------------- partial interleaved RoPE
__global__ __launch_bounds__(256) void rope_kernel(__bf16* __restrict__ Qb, __bf16* __restrict__ Kb) {
  const int idx = blockIdx.x * 256 + threadIdx.x;
  const int j  = idx & 15;
  const int s  = (idx >> 4) & (S_LEN - 1);
  const int bh = (idx >> 15) & (BH_TOT - 1);
  __bf16* base = (idx >> 20) ? Kb : Qb;
  bf16x2* p = (bf16x2*)(base + ((size_t)bh * S_LEN + s) * DHEAD) + j;
  bf16x2 v = *p;
  const float x1 = (float)v[0];
  const float x2 = (float)v[1];
  const float LOG2_10000 = 13.287712379549449f;
  const float inv = exp2f(-(float)j * (LOG2_10000 / 16.0f));
  const float ang = (float)s * inv;
  float sn, cs;
  sincosf(ang, &sn, &cs);
  bf16x2 o;
  o[0] = (__bf16)(x1 * cs - x2 * sn);
  o[1] = (__bf16)(x2 * cs + x1 * sn);
  *p = o;
}

// ---------------------------------------------------------------- flash attention R8
// 2 waves x 32 q = 64 q per block; grid (32, 32) = 1024 blocks, 8 waves/CU.
// KVBLK=32; K/V^T in a 4-deep LDS buffer ring (32 KB/block) via global_load_lds.
// DEPTH-3 COUNTED-VMCNT PIPELINE (T3+T4): each iteration issues tile kb+3 and waits
// s_waitcnt vmcnt(8) — tile kb's 4 loads retire, kb+1/kb+2/kb+3 stay in flight
// (~3 compute phases to cover HBM/L2 latency). Raw s_barrier AFTER the counted
// wait combines the two waves' half-stages (each wave's vmcnt covers its own DMAs).
// NO __syncthreads in the loop (it would emit the vmcnt(0) drain that kills depth).
// Buffer-overwrite safety: tile kb+3 -> buf[(kb+3)&3] = buf[(kb-1)&3], issued
// post-barrier when both waves have finished computing tile kb-1.
// Tail peeled with decreasing counts 8/8/4/0.
// Compute core identical to R7b (refcheck-verified): zero-shuffle PV, K-swizzle
// chunk^=row&7, V-swizzle chunk^=(row>>1)&3, setprio around MFMA clusters.
__global__ __launch_bounds__(128, 2) void attn_kernel(const __bf16* __restrict__ Qb,
                                                      const __bf16* __restrict__ Kb,
                                                      const __bf16* __restrict__ Vtb,
                                                      __bf16* __restrict__ AOb) {
  __shared__ __align__(16) __bf16 Ks[4][32 * 64];   // [key][d], swizzled, 4 KB each
  __shared__ __align__(16) __bf16 Vts[4][64 * 32];  // [d][key], swizzled, 4 KB each

  const int qt = blockIdx.x;           // 0..31
  const int bh = blockIdx.y;
  const int b = bh >> 4, h = bh & 15;
  const int t = threadIdx.x;
  const int wave = t >> 6, lane = t & 63;
  const int c31 = lane & 31, hi = lane >> 5;
  const int cx7 = c31 & 7;             // K-row swizzle key (row = c31)
  const int cxv = (c31 >> 1) & 3;      // V-row swizzle key (row = db*32+c31)
  const size_t head = (size_t)bh * S_LEN * DHEAD;
  const int q0w = qt * 64 + wave * 32; // this wave's first q

  // Q B-frags (resident): qf[s] = Q^T[k=d=s*16+hi*8+j][n=q=q0w+c31]
  bf16x8 qf[4];
#pragma unroll
  for (int s = 0; s < 4; ++s)
    qf[s] = *(const bf16x8*)(Qb + head + (size_t)(q0w + c31) * DHEAD + s * 16 + hi * 8);

  f32x16 zzero;
#pragma unroll
  for (int i = 0; i < 16; ++i) zzero[i] = 0.f;

  // O^T accumulators: lane holds d = db*32+(r&3)+8*(r>>2)+4*hi, q = c31.
  // ota <- 16-key chunk kc=0 of each tile, otb <- kc=1; summed in the epilogue.
  f32x16 ota[2], otb[2];
  ota[0] = zzero; ota[1] = zzero; otb[0] = zzero; otb[1] = zzero;
  float lp = 0.f;

  // staging: K tile = 256 16B units (row=u>>3 of 32, chunk=(u&7)^(row&7));
  //          V tile = 256 16B units (row=u>>2 of 64, chunk=(u&3)^((row>>1)&3));
  // 128 threads x 2 units each per matrix; LDS dst linear, source pre-swizzled.
  const __bf16* kg[2];
  const __bf16* vg[2];
  int lofK[2], lofV[2];
#pragma unroll
  for (int i = 0; i < 2; ++i) {
    const int u = t + 128 * i;
    const int rk = u >> 3, ck = (u & 7) ^ (rk & 7);
    kg[i] = Kb + head + (size_t)rk * DHEAD + ck * 8;
    lofK[i] = u * 8;
    const int rv = u >> 2, cv = (u & 3) ^ ((rv >> 1) & 3);
    vg[i] = Vtb + ((size_t)bh * DHEAD + rv) * S_LEN + cv * 8;
    lofV[i] = u * 8;
  }

  // prologue: stage tiles 0,1,2 into buffers 0,1,2 (12 DMAs/thread -> vmcnt=12)
#pragma unroll
  for (int tt = 0; tt < 3; ++tt) {
    const int ka = tt * (32 * DHEAD);
    const int va = tt * 32;
#pragma unroll
    for (int i = 0; i < 2; ++i) {
      gl2lds16(kg[i] + ka, &Ks[tt][lofK[i]]);
      gl2lds16(vg[i] + va, &Vts[tt][lofV[i]]);
    }
  }

// V^T A-frag (permuted k-slot order): element (hi,j) = V^T[d=db*32+c31][key=kc*16+4hi+(j<4?j:4+j)]
// = two b64 reads at 16B chunks kc*2, kc*2+1 (XOR-swizzled), byte offset hi*8.
#define VFRAG(CUR, db, kc)                                                                 \
  __builtin_bit_cast(bf16x8, (i32x4){                                                      \
      (int)__builtin_bit_cast(u32x2, *(const bf16x4*)(&Vts[CUR][((db) * 32 + c31) * 32 +   \
                                     ((((kc) * 2) ^ cxv) * 8) + hi * 4]))[0],              \
      (int)__builtin_bit_cast(u32x2, *(const bf16x4*)(&Vts[CUR][((db) * 32 + c31) * 32 +   \
                                     ((((kc) * 2) ^ cxv) * 8) + hi * 4]))[1],              \
      (int)__builtin_bit_cast(u32x2, *(const bf16x4*)(&Vts[CUR][((db) * 32 + c31) * 32 +   \
                                     ((((kc) * 2 + 1) ^ cxv) * 8) + hi * 4]))[0],          \
      (int)__builtin_bit_cast(u32x2, *(const bf16x4*)(&Vts[CUR][((db) * 32 + c31) * 32 +   \
                                     ((((kc) * 2 + 1) ^ cxv) * 8) + hi * 4]))[1]})

#define ATTN_TILE(KB, CUR, VM, PF)                                                         \
  {                                                                                        \
    asm volatile("s_waitcnt vmcnt(" #VM ")" ::: "memory");                                 \
    __builtin_amdgcn_s_barrier();                                                          \
    __builtin_amdgcn_sched_barrier(0);                                                     \
    if (PF) {                                                                              \
      const int ka = ((KB) + 3) * (32 * DHEAD);                                            \
      const int va = ((KB) + 3) * 32;                                                      \
      _Pragma("unroll")                                                                    \
      for (int i = 0; i < 2; ++i) {                                                        \
        gl2lds16(kg[i] + ka, &Ks[((CUR) + 3) & 3][lofK[i]]);                               \
        gl2lds16(vg[i] + va, &Vts[((CUR) + 3) & 3][lofV[i]]);                              \
      }                                                                                    \
    }                                                                                      \
    __builtin_amdgcn_sched_barrier(0);                                                     \
    bf16x8 kA[4];                                                                          \
    _Pragma("unroll")                                                                      \
    for (int s = 0; s < 4; ++s)                                                            \
      kA[s] = *(const bf16x8*)(&Ks[CUR][c31 * 64 + (((s * 2 + hi) ^ cx7) * 8)]);           \
    const bf16x8 vA00 = VFRAG(CUR, 0, 0);                                                  \
    const bf16x8 vA10 = VFRAG(CUR, 1, 0);                                                  \
    const bf16x8 vA01 = VFRAG(CUR, 0, 1);                                                  \
    const bf16x8 vA11 = VFRAG(CUR, 1, 1);                                                  \
    f32x16 z = zzero;                                                                      \
    __builtin_amdgcn_s_setprio(1);                                                         \
    _Pragma("unroll")                                                                      \
    for (int s = 0; s < 4; ++s) z = mfma3216(kA[s], qf[s], z);                             \
    __builtin_amdgcn_s_setprio(0);                                                         \
    float p[16];                                                                           \
    _Pragma("unroll")                                                                      \
    for (int r = 0; r < 16; ++r) p[r] = __builtin_amdgcn_exp2f(z[r]);                      \
    lp += (((p[0] + p[1]) + (p[2] + p[3])) + ((p[4] + p[5]) + (p[6] + p[7])))              \
        + (((p[8] + p[9]) + (p[10] + p[11])) + ((p[12] + p[13]) + (p[14] + p[15])));       \
    const bf16x8 f0 = pfragn(p[0], p[1], p[2], p[3], p[4], p[5], p[6], p[7]);              \
    const bf16x8 f1 = pfragn(p[8], p[9], p[10], p[11], p[12], p[13], p[14], p[15]);        \
    __builtin_amdgcn_s_setprio(1);                                                         \
    ota[0] = mfma3216(vA00, f0, ota[0]);                                                   \
    ota[1] = mfma3216(vA10, f0, ota[1]);                                                   \
    otb[0] = mfma3216(vA01, f1, otb[0]);                                                   \
    otb[1] = mfma3216(vA11, f1, otb[1]);                                                   \
    __builtin_amdgcn_s_setprio(0);                                                         \
  }

  // main loop: tiles 0..59 (prefetch reaches tile 62)
  for (int kbb = 0; kbb < 15; ++kbb) {
    const int kb4 = kbb * 4;
    ATTN_TILE(kb4 + 0, 0, 8, 1)
    ATTN_TILE(kb4 + 1, 1, 8, 1)
    ATTN_TILE(kb4 + 2, 2, 8, 1)
    ATTN_TILE(kb4 + 3, 3, 8, 1)
  }
  // tail: tile 60 prefetches 63; then drain with decreasing counts
  ATTN_TILE(60, 0, 8, 1)
  ATTN_TILE(61, 1, 8, 0)
  ATTN_TILE(62, 2, 4, 0)
  ATTN_TILE(63, 3, 0, 0)
#undef ATTN_TILE
#undef VFRAG

  // epilogue: merge split accumulators; l over full key range = lp + partner-half lp
#pragma unroll
  for (int i = 0; i < 16; ++i) { ota[0][i] += otb[0][i]; ota[1][i] += otb[1][i]; }
  const float l = lp + __shfl_xor(lp, 32);
  const float inv = 1.0f / l;
  const int q = q0w + c31;
#pragma unroll
  for (int db = 0; db < 2; ++db) {
#pragma unroll
    for (int rg = 0; rg < 4; ++rg) {
      bf16x4 o;
#pragma unroll
      for (int i = 0; i < 4; ++i) o[i] = (__bf16)(ota[db][rg * 4 + i] * inv);
      const int d0 = db * 32 + rg * 8 + hi * 4;
      *(bf16x4*)(AOb + ((size_t)(b * S_LEN + q)) * DMODEL + h * DHEAD + d0) = o;
    }
  }
}

// ---------------------------------------------------------------- launch
extern "C" void kernel_launch(void* const* d_in, const int* in_sizes, int n_in,
                              void* d_out, int out_size, void* d_ws, size_t ws_size,
                              hipStream_t stream) {
  const float* x    = (const float*)d_in[0];
  const float* Wqkv = (const float*)d_in[1];
  const float* bqkv = (const float*)d_in[2];
  const float* Wout = (const float*)d_in[3];
  const float* bout = (const float*)d_in[4];
  float* out = (float*)d_out;

  char* ws = (char*)d_ws;
  __bf16* xb    = (__bf16*)(ws + 0);                          //  8 MB (4096x1024)
  __bf16* Wqkvb = (__bf16*)(ws + (size_t)8  * 1024 * 1024);   //  6 MB (3072x1024)
  __bf16* Woutb = (__bf16*)(ws + (size_t)14 * 1024 * 1024);   //  2 MB (1024x1024)
  __bf16* Qb    = (__bf16*)(ws + (size_t)16 * 1024 * 1024);   //  8 MB [bh][s][d] (pre-scaled)
  __bf16* Kb    = (__bf16*)(ws + (size_t)24 * 1024 * 1024);   //  8 MB [bh][s][d]
  __bf16* Vtb   = (__bf16*)(ws + (size_t)32 * 1024 * 1024);   //  8 MB [bh][d][s]
  __bf16* AOb   = (__bf16*)(ws + (size_t)40 * 1024 * 1024);   //  8 MB [b][s][dm]

  cvt_kernel<<<(TOK * DMODEL) / 1024, 256, 0, stream>>>(x, xb, TOK * DMODEL);
  cvt_kernel<<<(NQKV * DMODEL) / 1024, 256, 0, stream>>>(Wqkv, Wqkvb, NQKV * DMODEL);
  cvt_kernel<<<(DMODEL * DMODEL) / 1024, 256, 0, stream>>>(Wout, Woutb, DMODEL * DMODEL);

  gemm_qkv_kernel<<<dim3(NQKV / 128, TOK / 128), 256, 0, stream>>>(xb, Wqkvb, bqkv, Qb, Kb, Vtb);

  rope_kernel<<<(2 * BH_TOT * S_LEN * 16) / 256, 256, 0, stream>>>(Qb, Kb);

  attn_kernel<<<dim3(S_LEN / 64, BH_TOT), 128, 0, stream>>>(Qb, Kb, Vtb, AOb);

  gemm_out_kernel<<<dim3(DMODEL / 128, TOK / 128), 256, 0, stream>>>(AOb, Woutb, bout, out);
}